// Round 5
// baseline (173.802 us; speedup 1.0000x reference)
//
#include <hip/hip_runtime.h>
#include <math.h>

#define NN   24          // nodes per graph
#define EPB  16          // graph elements per block
#define CSTR 28          // LDS column stride (floats): 24 + 4 pad, 16B aligned
#define ESTR 452         // per-elem stride: 16*28 + 4 → e-stride ≡ 4 banks mod 32
#define T    256
#define AT_OFF 2176      // A^T (24x24) in ws, 16B-aligned float offset

typedef float v2f __attribute__((ext_vector_type(2)));
typedef float v4f __attribute__((ext_vector_type(4)));

// Guaranteed packed math: d = a*b + c on 2xf32 register pairs.
static __device__ __forceinline__ v2f pkfma(v2f a, v2f b, v2f c) {
  asm("v_pk_fma_f32 %0, %1, %2, %0" : "+v"(c) : "v"(a), "v"(b));
  return c;
}
// c += a * broadcast(b.lo)  (src1 low half replicated via op_sel — no splat mov)
static __device__ __forceinline__ v2f pkfma_b0(v2f a, v2f b, v2f c) {
  asm("v_pk_fma_f32 %0, %1, %2, %0 op_sel:[0,0,0] op_sel_hi:[1,0,1]"
      : "+v"(c) : "v"(a), "v"(b));
  return c;
}
// c += a * broadcast(b.hi)
static __device__ __forceinline__ v2f pkfma_b1(v2f a, v2f b, v2f c) {
  asm("v_pk_fma_f32 %0, %1, %2, %0 op_sel:[0,1,0] op_sel_hi:[1,1,1]"
      : "+v"(c) : "v"(a), "v"(b));
  return c;
}

// ws layout (floats): [0..575] A(24x24) | [576..2111] Wc(768x2) | [2112..2113] bc(2)
//                     | [2176..2751] AT(24x24)   (assumes ws_size >= 11008 B)

__global__ void prep_kernel(const int* __restrict__ ei, int ec,
                            const float* __restrict__ fcw1, const float* __restrict__ fcb1,
                            const float* __restrict__ fcw2, const float* __restrict__ fcb2,
                            float* __restrict__ ws) {
  int t = threadIdx.x;
  if (blockIdx.x == 0) {
    __shared__ float deg[NN];
    __shared__ float dinv[NN];
    __shared__ float As[NN*NN];
    __shared__ int s_is64;
    if (t == 0) s_is64 = 1;
    if (t < NN) deg[t] = 1.0f;            // self-loop contribution
    for (int k = t; k < NN*NN; k += T) As[k] = 0.0f;
    __syncthreads();
    // dtype sniff: int64 edge_index viewed as int32 has all odd (high) words == 0
    for (int k = t; k < 2*ec; k += T) {
      if (ei[2*k + 1] != 0) atomicExch(&s_is64, 0);
    }
    __syncthreads();
    int is64 = s_is64;
    for (int k = t; k < ec; k += T) {
      int d = is64 ? ei[2*(ec + k)] : ei[ec + k];
      atomicAdd(&deg[d], 1.0f);
    }
    __syncthreads();
    if (t < NN) dinv[t] = 1.0f / sqrtf(deg[t]);
    __syncthreads();
    for (int k = t; k < ec; k += T) {
      int s = is64 ? ei[2*k]        : ei[k];
      int d = is64 ? ei[2*(ec + k)] : ei[ec + k];
      atomicAdd(&As[d*NN + s], dinv[s]*dinv[d]);
    }
    if (t < NN) atomicAdd(&As[t*NN + t], dinv[t]*dinv[t]);  // self loop
    __syncthreads();
    for (int k = t; k < NN*NN; k += T) {
      float a = As[k];
      int r = k / NN, c = k % NN;
      ws[k] = a;                       // A (row-major), used by g1 stage
      ws[AT_OFF + c*NN + r] = a;       // A^T, used by column-form A-mix
    }
    if (t < 2) {
      float acc = fcb2[t];
      for (int k = 0; k < 128; ++k) acc += fcb1[k]*fcw2[k*2 + t];
      ws[2112 + t] = acc;
    }
  } else {
    // Wc = fcw1 @ fcw2 : blocks 1..8 compute 96 rows each (fcw2 transposed in LDS)
    __shared__ __align__(16) float w2t[256];
    for (int k = t; k < 256; k += T) w2t[(k & 1)*128 + (k >> 1)] = fcw2[k];
    __syncthreads();
    int r0 = (blockIdx.x - 1) * 96;
    for (int idx = t; idx < 96*2; idx += T) {
      int r = r0 + (idx >> 1), c = idx & 1;
      const v4f* w1r = (const v4f*)(fcw1 + r*128);
      const v4f* w2v = (const v4f*)(w2t + c*128);
      v4f s = (v4f){0.f, 0.f, 0.f, 0.f};
      #pragma unroll
      for (int k = 0; k < 32; ++k) s = w1r[k]*w2v[k] + s;
      ws[576 + r*2 + c] = (s.x + s.y) + (s.z + s.w);
    }
  }
}

// Merged step: gbuf holds g_l = A @ h_{l-1} (FIN cols per elem).
// W-mix: h col f = relu(g_l @ W + b) held as 12 v2f pairs (asm v_pk_fma_f32).
// BARRIER, then COLUMN-form A-mix: out[i] = sum_j AT[j][i]*h[j], accumulated in
// aligned v2f pairs. AT arrives via LDS broadcast reads (wave-uniform address →
// same-address broadcast, conflict-free, vector-pipe batched); h[j] broadcast
// comes free via op_sel. Zero scalar-pipe / VMEM traffic in the inner loop.
template<int FIN, int FOUT, int SPLIT>
__device__ __forceinline__ void merged_layer(const float* ATsh, float* gbuf,
                                             const float* Ws, const float* bs, int t) {
  constexpr int NCOLS = EPB*FOUT;       // 64/64/128/128/256/256
  constexpr int CL    = NN/SPLIT;       // 6/6/12/12/24/24
  int col = t & (NCOLS - 1);
  int i0  = __builtin_amdgcn_readfirstlane((t / NCOLS) * CL);  // wave-uniform
  int e = col / FOUT;
  int f = col & (FOUT - 1);
  const float* ib = gbuf + e*ESTR;
  // hoist W column + bias (batched LDS b32 reads, latency overlapped)
  float wcol[FIN];
  #pragma unroll
  for (int fi = 0; fi < FIN; ++fi) wcol[fi] = Ws[fi*FOUT + f];
  float bf = bs[f];
  v2f hh[12];
  #pragma unroll
  for (int k = 0; k < 12; ++k) hh[k] = (v2f){bf, bf};
  #pragma unroll
  for (int fi = 0; fi < FIN; ++fi) {
    v2f w2 = (v2f){wcol[fi], wcol[fi]};
    const v4f* c4 = (const v4f*)(ib + fi*CSTR);
    #pragma unroll
    for (int k = 0; k < 6; ++k) {
      v4f v = c4[k];
      v2f lo = __builtin_shufflevector(v, v, 0, 1);
      v2f hi = __builtin_shufflevector(v, v, 2, 3);
      hh[2*k]   = pkfma(lo, w2, hh[2*k]);
      hh[2*k+1] = pkfma(hi, w2, hh[2*k+1]);
    }
  }
  #pragma unroll
  for (int k = 0; k < 12; ++k)
    hh[k] = __builtin_elementwise_max(hh[k], (v2f){0.f, 0.f});
  __syncthreads();           // all gbuf reads complete before in-place overwrite
  // A-mix, column form over rows i0..i0+CL-1; jp runs over h pairs (elems 0/1)
  float* ob = gbuf + e*ESTR + f*CSTR + i0;
  constexpr int NV = CL/2;
  v2f acc[NV] = {};
  #pragma unroll
  for (int jp = 0; jp < 12; ++jp) {
    v2f hp = hh[jp];
    const float* atpA = ATsh + (2*jp)*NN + i0;      // wave-uniform LDS addr →
    const float* atpB = ATsh + (2*jp + 1)*NN + i0;  // broadcast ds_read
    if constexpr (CL == 6) {
      const v2f* at2A = (const v2f*)atpA;   // 8B-aligned (i0 multiple of 6)
      const v2f* at2B = (const v2f*)atpB;
      #pragma unroll
      for (int k = 0; k < 3; ++k) {
        acc[k] = pkfma_b0(at2A[k], hp, acc[k]);
        acc[k] = pkfma_b1(at2B[k], hp, acc[k]);
      }
    } else {
      const v4f* at4A = (const v4f*)atpA;   // 16B-aligned (i0 multiple of 12)
      const v4f* at4B = (const v4f*)atpB;
      #pragma unroll
      for (int k = 0; k < NV/2; ++k) {
        v4f a4 = at4A[k];
        v4f b4 = at4B[k];
        acc[2*k]   = pkfma_b0(__builtin_shufflevector(a4, a4, 0, 1), hp, acc[2*k]);
        acc[2*k+1] = pkfma_b0(__builtin_shufflevector(a4, a4, 2, 3), hp, acc[2*k+1]);
        acc[2*k]   = pkfma_b1(__builtin_shufflevector(b4, b4, 0, 1), hp, acc[2*k]);
        acc[2*k+1] = pkfma_b1(__builtin_shufflevector(b4, b4, 2, 3), hp, acc[2*k+1]);
      }
    }
  }
  #pragma unroll
  for (int k = 0; k < NV; ++k) *(v2f*)(ob + 2*k) = acc[k];
}

__global__ __launch_bounds__(256, 4) void gcn_main(
    const float* __restrict__ x, const float* __restrict__ ws,
    const float* __restrict__ W1, const float* __restrict__ b1,
    const float* __restrict__ W2, const float* __restrict__ b2,
    const float* __restrict__ W3, const float* __restrict__ b3,
    const float* __restrict__ W4, const float* __restrict__ b4,
    const float* __restrict__ W5, const float* __restrict__ b5,
    const float* __restrict__ W6, const float* __restrict__ b6,
    const float* __restrict__ W7, const float* __restrict__ b7,
    float* __restrict__ out) {
  __shared__ __align__(16) float gbuf[EPB*ESTR];  // 28928 B, single in-place buffer
  __shared__ float Wsh[500];                      // W1..W6; W7 read from global/L1
  __shared__ __align__(16) float bsh[88];
  __shared__ __align__(16) float Ash[NN*NN];      // A^T, broadcast-read in A-mix
  int t = threadIdx.x;

  // stage layer weights/biases into LDS
  {
    const float* Wp[6] = {W1,W2,W3,W4,W5,W6};
    const float* bp[7] = {b1,b2,b3,b4,b5,b6,b7};
    const int wsz[6] = {4,16,32,64,128,256};
    const int wof[6] = {0,4,20,52,116,244};
    const int bsz[7] = {4,4,8,8,16,16,32};
    const int bof[7] = {0,4,8,16,24,40,56};
    #pragma unroll
    for (int l = 0; l < 6; ++l) {
      for (int k = t; k < wsz[l]; k += T) Wsh[wof[l] + k] = Wp[l][k];
    }
    #pragma unroll
    for (int l = 0; l < 7; ++l) {
      if (t < bsz[l]) bsh[bof[l] + t] = bp[l][t];
    }
  }
  // stage A^T into LDS (144 x float4)
  if (t < NN*NN/4) ((v4f*)Ash)[t] = ((const v4f*)(ws + AT_OFF))[t];
  // stage x tile into column slot 1 of each elem (col 0 gets g1 = A@x)
  {
    const float* xg = x + (size_t)blockIdx.x * (EPB*NN);
    if (t < EPB*NN/4) {
      float4 v = ((const float4*)xg)[t];
      int e = t/6, k = t - e*6;
      ((float4*)(gbuf + e*ESTR + CSTR))[k] = v;
    }
  }
  __syncthreads();

  // g1 = A @ x : 384 tasks (e, i); A rows per-lane from global (2.3 KB, L1-hot)
  {
    int e = t & 15, i = t >> 4;          // i in 0..15
    const float4* xv = (const float4*)(gbuf + e*ESTR + CSTR);
    const float4* Ar = (const float4*)(ws + i*NN);
    float acc = 0.f;
    #pragma unroll
    for (int k = 0; k < 6; ++k) {
      float4 a = Ar[k]; float4 v = xv[k];
      acc += a.x*v.x + a.y*v.y + a.z*v.z + a.w*v.w;
    }
    gbuf[e*ESTR + i] = acc;
    if (t < 128) {
      int i2 = 16 + (t >> 4);            // i in 16..23
      const float4* Ar2 = (const float4*)(ws + i2*NN);
      float acc2 = 0.f;
      #pragma unroll
      for (int k = 0; k < 6; ++k) {
        float4 a = Ar2[k]; float4 v = xv[k];
        acc2 += a.x*v.x + a.y*v.y + a.z*v.z + a.w*v.w;
      }
      gbuf[e*ESTR + i2] = acc2;
    }
  }
  __syncthreads();

  merged_layer<1, 4, 4>(Ash, gbuf, Wsh+0,   bsh+0,  t); __syncthreads();
  merged_layer<4, 4, 4>(Ash, gbuf, Wsh+4,   bsh+4,  t); __syncthreads();
  merged_layer<4, 8, 2>(Ash, gbuf, Wsh+20,  bsh+8,  t); __syncthreads();
  merged_layer<8, 8, 2>(Ash, gbuf, Wsh+52,  bsh+16, t); __syncthreads();
  merged_layer<8,16, 1>(Ash, gbuf, Wsh+116, bsh+24, t); __syncthreads();
  merged_layer<16,16,1>(Ash, gbuf, Wsh+244, bsh+40, t); __syncthreads();

  // L7 + composed FC + log_softmax (column form, asm packed math):
  // hh as 12 v2f pairs; P-mix uses op_sel broadcasts so each h element costs
  // exactly one pk-fma. Wc loads are per-lane (f-dependent) → coalesced VMEM.
  {
    const float* Wc = ws + 576;
    float bc0 = ws[2112], bc1 = ws[2113];
    #pragma unroll
    for (int r = 0; r < 2; ++r) {
      int col = t + r*T;               // 512 columns = 16 elems x 32 feats
      int e = col >> 5, f = col & 31;
      const float* ib = gbuf + e*ESTR;
      float bf = bsh[56 + f];
      v2f hh[12];
      #pragma unroll
      for (int k = 0; k < 12; ++k) hh[k] = (v2f){bf, bf};
      #pragma unroll
      for (int fi = 0; fi < 16; ++fi) {
        float w = W7[fi*32 + f];       // global, L1-cached, coalesced
        v2f w2 = (v2f){w, w};
        const v4f* c4 = (const v4f*)(ib + fi*CSTR);
        #pragma unroll
        for (int k = 0; k < 6; ++k) {
          v4f v = c4[k];
          v2f lo = __builtin_shufflevector(v, v, 0, 1);
          v2f hi = __builtin_shufflevector(v, v, 2, 3);
          hh[2*k]   = pkfma(lo, w2, hh[2*k]);
          hh[2*k+1] = pkfma(hi, w2, hh[2*k+1]);
        }
      }
      #pragma unroll
      for (int k = 0; k < 12; ++k)
        hh[k] = __builtin_elementwise_max(hh[k], (v2f){0.f, 0.f});
      v2f p = (v2f){0.f, 0.f};         // (p0, p1)
      #pragma unroll
      for (int kp = 0; kp < 12; ++kp) {
        v2f hp = hh[kp];
        v2f wcA = *(const v2f*)(Wc + ((2*kp)*32 + f)*2);
        v2f wcB = *(const v2f*)(Wc + ((2*kp + 1)*32 + f)*2);
        p = pkfma_b0(wcA, hp, p);
        p = pkfma_b1(wcB, hp, p);
      }
      float p0 = p.x, p1 = p.y;
      #pragma unroll
      for (int m = 1; m < 32; m <<= 1) {
        p0 += __shfl_xor(p0, m, 32);
        p1 += __shfl_xor(p1, m, 32);
      }
      if (f < 2) {
        float z0 = p0 + bc0, z1 = p1 + bc1;
        float mx = fmaxf(z0, z1);
        float lse = mx + logf(expf(z0 - mx) + expf(z1 - mx));
        int eg = blockIdx.x*EPB + e;
        out[eg*2 + f] = (f == 0 ? z0 : z1) - lse;
      }
    }
  }
}

extern "C" void kernel_launch(void* const* d_in, const int* in_sizes, int n_in,
                              void* d_out, int out_size, void* d_ws, size_t ws_size,
                              hipStream_t stream) {
  const float* x    = (const float*)d_in[0];
  const int*   ei   = (const int*)  d_in[1];
  const float* W1   = (const float*)d_in[2];  const float* b1 = (const float*)d_in[3];
  const float* W2   = (const float*)d_in[4];  const float* b2 = (const float*)d_in[5];
  const float* W3   = (const float*)d_in[6];  const float* b3 = (const float*)d_in[7];
  const float* W4   = (const float*)d_in[8];  const float* b4 = (const float*)d_in[9];
  const float* W5   = (const float*)d_in[10]; const float* b5 = (const float*)d_in[11];
  const float* W6   = (const float*)d_in[12]; const float* b6 = (const float*)d_in[13];
  const float* W7   = (const float*)d_in[14]; const float* b7 = (const float*)d_in[15];
  const float* fcw1 = (const float*)d_in[16]; const float* fcb1 = (const float*)d_in[17];
  const float* fcw2 = (const float*)d_in[18]; const float* fcb2 = (const float*)d_in[19];
  float* out = (float*)d_out;
  float* ws  = (float*)d_ws;
  int ec = in_sizes[1] / 2;        // 96 edges
  int B  = in_sizes[0] / NN;       // 32768

  hipLaunchKernelGGL(prep_kernel, dim3(9), dim3(T), 0, stream,
                     ei, ec, fcw1, fcb1, fcw2, fcb2, ws);
  hipLaunchKernelGGL(gcn_main, dim3(B/EPB), dim3(T), 0, stream,
                     x, ws, W1,b1, W2,b2, W3,b3, W4,b4, W5,b5, W6,b6, W7,b7, out);
}

// Round 6
// 157.614 us; speedup vs baseline: 1.1027x; 1.1027x over previous
//
#include <hip/hip_runtime.h>
#include <math.h>

#define NN   24          // nodes per graph
#define EPB  16          // graph elements per block
#define CSTR 24          // LDS column stride (floats): 24 floats = 96 B, 16B-aligned
#define ESTR 388         // per-elem stride: 16*24 + 4 → e-stride ≡ 4 banks mod 32
#define T    256
#define AT_OFF 2176      // A^T (24x24) in ws, 16B-aligned float offset

typedef float v2f __attribute__((ext_vector_type(2)));
typedef float v4f __attribute__((ext_vector_type(4)));

// Guaranteed packed math: d = a*b + c on 2xf32 register pairs.
static __device__ __forceinline__ v2f pkfma(v2f a, v2f b, v2f c) {
  asm("v_pk_fma_f32 %0, %1, %2, %0" : "+v"(c) : "v"(a), "v"(b));
  return c;
}
// c += a * broadcast(b.lo)  (src1 low half replicated via op_sel — no splat mov)
static __device__ __forceinline__ v2f pkfma_b0(v2f a, v2f b, v2f c) {
  asm("v_pk_fma_f32 %0, %1, %2, %0 op_sel:[0,0,0] op_sel_hi:[1,0,1]"
      : "+v"(c) : "v"(a), "v"(b));
  return c;
}
// c += a * broadcast(b.hi)
static __device__ __forceinline__ v2f pkfma_b1(v2f a, v2f b, v2f c) {
  asm("v_pk_fma_f32 %0, %1, %2, %0 op_sel:[0,1,0] op_sel_hi:[1,1,1]"
      : "+v"(c) : "v"(a), "v"(b));
  return c;
}
// Same, but a (src0) delivered from an SGPR pair — scalar-pipe operand flow.
static __device__ __forceinline__ v2f pkfma_sb0(v2f a, v2f b, v2f c) {
  asm("v_pk_fma_f32 %0, %1, %2, %0 op_sel:[0,0,0] op_sel_hi:[1,0,1]"
      : "+v"(c) : "s"(a), "v"(b));
  return c;
}
static __device__ __forceinline__ v2f pkfma_sb1(v2f a, v2f b, v2f c) {
  asm("v_pk_fma_f32 %0, %1, %2, %0 op_sel:[0,1,0] op_sel_hi:[1,1,1]"
      : "+v"(c) : "s"(a), "v"(b));
  return c;
}

// ws layout (floats): [0..575] A(24x24) | [576..2111] Wc(768x2) | [2112..2113] bc(2)
//                     | [2176..2751] AT(24x24)   (assumes ws_size >= 11008 B)

__global__ void prep_kernel(const int* __restrict__ ei, int ec,
                            const float* __restrict__ fcw1, const float* __restrict__ fcb1,
                            const float* __restrict__ fcw2, const float* __restrict__ fcb2,
                            float* __restrict__ ws) {
  int t = threadIdx.x;
  if (blockIdx.x == 0) {
    __shared__ float deg[NN];
    __shared__ float dinv[NN];
    __shared__ float As[NN*NN];
    __shared__ int s_is64;
    if (t == 0) s_is64 = 1;
    if (t < NN) deg[t] = 1.0f;            // self-loop contribution
    for (int k = t; k < NN*NN; k += T) As[k] = 0.0f;
    __syncthreads();
    // dtype sniff: int64 edge_index viewed as int32 has all odd (high) words == 0
    for (int k = t; k < 2*ec; k += T) {
      if (ei[2*k + 1] != 0) atomicExch(&s_is64, 0);
    }
    __syncthreads();
    int is64 = s_is64;
    for (int k = t; k < ec; k += T) {
      int d = is64 ? ei[2*(ec + k)] : ei[ec + k];
      atomicAdd(&deg[d], 1.0f);
    }
    __syncthreads();
    if (t < NN) dinv[t] = 1.0f / sqrtf(deg[t]);
    __syncthreads();
    for (int k = t; k < ec; k += T) {
      int s = is64 ? ei[2*k]        : ei[k];
      int d = is64 ? ei[2*(ec + k)] : ei[ec + k];
      atomicAdd(&As[d*NN + s], dinv[s]*dinv[d]);
    }
    if (t < NN) atomicAdd(&As[t*NN + t], dinv[t]*dinv[t]);  // self loop
    __syncthreads();
    for (int k = t; k < NN*NN; k += T) {
      float a = As[k];
      int r = k / NN, c = k % NN;
      ws[k] = a;                       // A (row-major), used by g1 stage
      ws[AT_OFF + c*NN + r] = a;       // A^T, used by column-form A-mix
    }
    if (t < 2) {
      float acc = fcb2[t];
      for (int k = 0; k < 128; ++k) acc += fcb1[k]*fcw2[k*2 + t];
      ws[2112 + t] = acc;
    }
  } else {
    // Wc = fcw1 @ fcw2 : blocks 1..8 compute 96 rows each (fcw2 transposed in LDS)
    __shared__ __align__(16) float w2t[256];
    for (int k = t; k < 256; k += T) w2t[(k & 1)*128 + (k >> 1)] = fcw2[k];
    __syncthreads();
    int r0 = (blockIdx.x - 1) * 96;
    for (int idx = t; idx < 96*2; idx += T) {
      int r = r0 + (idx >> 1), c = idx & 1;
      const v4f* w1r = (const v4f*)(fcw1 + r*128);
      const v4f* w2v = (const v4f*)(w2t + c*128);
      v4f s = (v4f){0.f, 0.f, 0.f, 0.f};
      #pragma unroll
      for (int k = 0; k < 32; ++k) s = w1r[k]*w2v[k] + s;
      ws[576 + r*2 + c] = (s.x + s.y) + (s.z + s.w);
    }
  }
}

// Merged step: gbuf holds g_l = A @ h_{l-1} (FIN cols per elem).
// W-mix: h col f = relu(g_l @ W + b) held as 12 v2f pairs (asm v_pk_fma_f32).
// BARRIER, then COLUMN-form A-mix: out[i] = sum_j AT[j][i]*h[j].
// HYBRID operand delivery: first 2/3 of each row-slice via SCALAR pipe
// (s_load → SGPR-pair src0), last 1/3 via LDS broadcast (wave-uniform ds_read)
// — splits the serial operand stream across two independent pipes.
template<int FIN, int FOUT, int SPLIT>
__device__ __forceinline__ void merged_layer(const float* __restrict__ ATg,
                                             const float* Ash, float* gbuf,
                                             const float* Ws, const float* bs, int t) {
  constexpr int NCOLS = EPB*FOUT;       // 64/64/128/128/256/256
  constexpr int CL    = NN/SPLIT;       // 6/6/12/12/24/24
  constexpr int NV    = CL/2;
  constexpr int KS    = (CL == 6) ? 2 : (CL == 12 ? 4 : 8);  // SMEM share
  int col = t & (NCOLS - 1);
  int i0  = __builtin_amdgcn_readfirstlane((t / NCOLS) * CL);  // wave-uniform
  int e = col / FOUT;
  int f = col & (FOUT - 1);
  const float* ib = gbuf + e*ESTR;
  // hoist W column + bias (batched LDS b32 reads, latency overlapped)
  float wcol[FIN];
  #pragma unroll
  for (int fi = 0; fi < FIN; ++fi) wcol[fi] = Ws[fi*FOUT + f];
  float bf = bs[f];
  v2f hh[12];
  #pragma unroll
  for (int k = 0; k < 12; ++k) hh[k] = (v2f){bf, bf};
  #pragma unroll
  for (int fi = 0; fi < FIN; ++fi) {
    v2f w2 = (v2f){wcol[fi], wcol[fi]};
    const v4f* c4 = (const v4f*)(ib + fi*CSTR);
    #pragma unroll
    for (int k = 0; k < 6; ++k) {
      v4f v = c4[k];
      v2f lo = __builtin_shufflevector(v, v, 0, 1);
      v2f hi = __builtin_shufflevector(v, v, 2, 3);
      hh[2*k]   = pkfma(lo, w2, hh[2*k]);
      hh[2*k+1] = pkfma(hi, w2, hh[2*k+1]);
    }
  }
  #pragma unroll
  for (int k = 0; k < 12; ++k)
    hh[k] = __builtin_elementwise_max(hh[k], (v2f){0.f, 0.f});
  __syncthreads();           // all gbuf reads complete before in-place overwrite
  // A-mix, column form over rows i0..i0+CL-1; jp runs over h pairs (elems 0/1)
  float* ob = gbuf + e*ESTR + f*CSTR + i0;
  v2f acc[NV] = {};
  #pragma unroll
  for (int jp = 0; jp < 12; ++jp) {
    v2f hp = hh[jp];
    const v2f* gA = (const v2f*)(ATg + (2*jp)*NN + i0);      // uniform → s_load
    const v2f* gB = (const v2f*)(ATg + (2*jp + 1)*NN + i0);
    #pragma unroll
    for (int k = 0; k < KS; ++k) {
      acc[k] = pkfma_sb0(gA[k], hp, acc[k]);
      acc[k] = pkfma_sb1(gB[k], hp, acc[k]);
    }
    const float* lA = Ash + (2*jp)*NN + i0;                  // uniform → ds_read
    const float* lB = Ash + (2*jp + 1)*NN + i0;              //   (broadcast)
    if constexpr (CL == 6) {
      acc[2] = pkfma_b0(((const v2f*)lA)[2], hp, acc[2]);
      acc[2] = pkfma_b1(((const v2f*)lB)[2], hp, acc[2]);
    } else {
      constexpr int NQ = (NV - KS) / 2;   // 1 (CL=12) or 2 (CL=24) v4f per row
      const v4f* qA = (const v4f*)(lA + 2*KS);
      const v4f* qB = (const v4f*)(lB + 2*KS);
      #pragma unroll
      for (int q = 0; q < NQ; ++q) {
        v4f a4 = qA[q], b4 = qB[q];
        acc[KS+2*q]   = pkfma_b0(__builtin_shufflevector(a4,a4,0,1), hp, acc[KS+2*q]);
        acc[KS+2*q+1] = pkfma_b0(__builtin_shufflevector(a4,a4,2,3), hp, acc[KS+2*q+1]);
        acc[KS+2*q]   = pkfma_b1(__builtin_shufflevector(b4,b4,0,1), hp, acc[KS+2*q]);
        acc[KS+2*q+1] = pkfma_b1(__builtin_shufflevector(b4,b4,2,3), hp, acc[KS+2*q+1]);
      }
    }
  }
  #pragma unroll
  for (int k = 0; k < NV; ++k) *(v2f*)(ob + 2*k) = acc[k];
}

__global__ __launch_bounds__(256, 4) void gcn_main(
    const float* __restrict__ x, const float* __restrict__ ws,
    const float* __restrict__ W1, const float* __restrict__ b1,
    const float* __restrict__ W2, const float* __restrict__ b2,
    const float* __restrict__ W3, const float* __restrict__ b3,
    const float* __restrict__ W4, const float* __restrict__ b4,
    const float* __restrict__ W5, const float* __restrict__ b5,
    const float* __restrict__ W6, const float* __restrict__ b6,
    const float* __restrict__ W7, const float* __restrict__ b7,
    float* __restrict__ out) {
  __shared__ __align__(16) float gbuf[EPB*ESTR];  // 24832 B, single in-place buffer
  __shared__ float Wsh[500];                      // W1..W6; W7 read from global/L1
  __shared__ __align__(16) float bsh[88];
  __shared__ __align__(16) float Ash[NN*NN];      // A^T for the LDS-broadcast share
  int t = threadIdx.x;
  const float* ATg = ws + AT_OFF;       // wave-uniform: scalar-pipe delivery

  // stage layer weights/biases into LDS
  {
    const float* Wp[6] = {W1,W2,W3,W4,W5,W6};
    const float* bp[7] = {b1,b2,b3,b4,b5,b6,b7};
    const int wsz[6] = {4,16,32,64,128,256};
    const int wof[6] = {0,4,20,52,116,244};
    const int bsz[7] = {4,4,8,8,16,16,32};
    const int bof[7] = {0,4,8,16,24,40,56};
    #pragma unroll
    for (int l = 0; l < 6; ++l) {
      for (int k = t; k < wsz[l]; k += T) Wsh[wof[l] + k] = Wp[l][k];
    }
    #pragma unroll
    for (int l = 0; l < 7; ++l) {
      if (t < bsz[l]) bsh[bof[l] + t] = bp[l][t];
    }
  }
  // stage A^T into LDS (144 x float4)
  if (t < NN*NN/4) ((v4f*)Ash)[t] = ((const v4f*)(ws + AT_OFF))[t];
  // stage x tile into column slot 1 of each elem (col 0 gets g1 = A@x)
  {
    const float* xg = x + (size_t)blockIdx.x * (EPB*NN);
    if (t < EPB*NN/4) {
      float4 v = ((const float4*)xg)[t];
      int e = t/6, k = t - e*6;
      ((float4*)(gbuf + e*ESTR + CSTR))[k] = v;
    }
  }
  __syncthreads();

  // g1 = A @ x : 384 tasks (e, i); A rows per-lane from global (2.3 KB, L1-hot)
  {
    int e = t & 15, i = t >> 4;          // i in 0..15
    const float4* xv = (const float4*)(gbuf + e*ESTR + CSTR);
    const float4* Ar = (const float4*)(ws + i*NN);
    float acc = 0.f;
    #pragma unroll
    for (int k = 0; k < 6; ++k) {
      float4 a = Ar[k]; float4 v = xv[k];
      acc += a.x*v.x + a.y*v.y + a.z*v.z + a.w*v.w;
    }
    gbuf[e*ESTR + i] = acc;
    if (t < 128) {
      int i2 = 16 + (t >> 4);            // i in 16..23
      const float4* Ar2 = (const float4*)(ws + i2*NN);
      float acc2 = 0.f;
      #pragma unroll
      for (int k = 0; k < 6; ++k) {
        float4 a = Ar2[k]; float4 v = xv[k];
        acc2 += a.x*v.x + a.y*v.y + a.z*v.z + a.w*v.w;
      }
      gbuf[e*ESTR + i2] = acc2;
    }
  }
  __syncthreads();

  merged_layer<1, 4, 4>(ATg, Ash, gbuf, Wsh+0,   bsh+0,  t); __syncthreads();
  merged_layer<4, 4, 4>(ATg, Ash, gbuf, Wsh+4,   bsh+4,  t); __syncthreads();
  merged_layer<4, 8, 2>(ATg, Ash, gbuf, Wsh+20,  bsh+8,  t); __syncthreads();
  merged_layer<8, 8, 2>(ATg, Ash, gbuf, Wsh+52,  bsh+16, t); __syncthreads();
  merged_layer<8,16, 1>(ATg, Ash, gbuf, Wsh+116, bsh+24, t); __syncthreads();
  merged_layer<16,16,1>(ATg, Ash, gbuf, Wsh+244, bsh+40, t); __syncthreads();

  // L7 + composed FC + log_softmax (column form, asm packed math):
  // hh as 12 v2f pairs; P-mix uses op_sel broadcasts so each h element costs
  // exactly one pk-fma. Wc loads are per-lane (f-dependent) → coalesced VMEM.
  {
    const float* Wc = ws + 576;
    float bc0 = ws[2112], bc1 = ws[2113];
    #pragma unroll
    for (int r = 0; r < 2; ++r) {
      int col = t + r*T;               // 512 columns = 16 elems x 32 feats
      int e = col >> 5, f = col & 31;
      const float* ib = gbuf + e*ESTR;
      float bf = bsh[56 + f];
      v2f hh[12];
      #pragma unroll
      for (int k = 0; k < 12; ++k) hh[k] = (v2f){bf, bf};
      #pragma unroll
      for (int fi = 0; fi < 16; ++fi) {
        float w = W7[fi*32 + f];       // global, L1-cached, coalesced
        v2f w2 = (v2f){w, w};
        const v4f* c4 = (const v4f*)(ib + fi*CSTR);
        #pragma unroll
        for (int k = 0; k < 6; ++k) {
          v4f v = c4[k];
          v2f lo = __builtin_shufflevector(v, v, 0, 1);
          v2f hi = __builtin_shufflevector(v, v, 2, 3);
          hh[2*k]   = pkfma(lo, w2, hh[2*k]);
          hh[2*k+1] = pkfma(hi, w2, hh[2*k+1]);
        }
      }
      #pragma unroll
      for (int k = 0; k < 12; ++k)
        hh[k] = __builtin_elementwise_max(hh[k], (v2f){0.f, 0.f});
      v2f p = (v2f){0.f, 0.f};         // (p0, p1)
      #pragma unroll
      for (int kp = 0; kp < 12; ++kp) {
        v2f hp = hh[kp];
        v2f wcA = *(const v2f*)(Wc + ((2*kp)*32 + f)*2);
        v2f wcB = *(const v2f*)(Wc + ((2*kp + 1)*32 + f)*2);
        p = pkfma_b0(wcA, hp, p);
        p = pkfma_b1(wcB, hp, p);
      }
      float p0 = p.x, p1 = p.y;
      #pragma unroll
      for (int m = 1; m < 32; m <<= 1) {
        p0 += __shfl_xor(p0, m, 32);
        p1 += __shfl_xor(p1, m, 32);
      }
      if (f < 2) {
        float z0 = p0 + bc0, z1 = p1 + bc1;
        float mx = fmaxf(z0, z1);
        float lse = mx + logf(expf(z0 - mx) + expf(z1 - mx));
        int eg = blockIdx.x*EPB + e;
        out[eg*2 + f] = (f == 0 ? z0 : z1) - lse;
      }
    }
  }
}

extern "C" void kernel_launch(void* const* d_in, const int* in_sizes, int n_in,
                              void* d_out, int out_size, void* d_ws, size_t ws_size,
                              hipStream_t stream) {
  const float* x    = (const float*)d_in[0];
  const int*   ei   = (const int*)  d_in[1];
  const float* W1   = (const float*)d_in[2];  const float* b1 = (const float*)d_in[3];
  const float* W2   = (const float*)d_in[4];  const float* b2 = (const float*)d_in[5];
  const float* W3   = (const float*)d_in[6];  const float* b3 = (const float*)d_in[7];
  const float* W4   = (const float*)d_in[8];  const float* b4 = (const float*)d_in[9];
  const float* W5   = (const float*)d_in[10]; const float* b5 = (const float*)d_in[11];
  const float* W6   = (const float*)d_in[12]; const float* b6 = (const float*)d_in[13];
  const float* W7   = (const float*)d_in[14]; const float* b7 = (const float*)d_in[15];
  const float* fcw1 = (const float*)d_in[16]; const float* fcb1 = (const float*)d_in[17];
  const float* fcw2 = (const float*)d_in[18]; const float* fcb2 = (const float*)d_in[19];
  float* out = (float*)d_out;
  float* ws  = (float*)d_ws;
  int ec = in_sizes[1] / 2;        // 96 edges
  int B  = in_sizes[0] / NN;       // 32768

  hipLaunchKernelGGL(prep_kernel, dim3(9), dim3(T), 0, stream,
                     ei, ec, fcw1, fcb1, fcw2, fcb2, ws);
  hipLaunchKernelGGL(gcn_main, dim3(B/EPB), dim3(T), 0, stream,
                     x, ws, W1,b1, W2,b2, W3,b3, W4,b4, W5,b5, W6,b6, W7,b7, out);
}